// Round 10
// baseline (1294.322 us; speedup 1.0000x reference)
//
#include <hip/hip_runtime.h>

#define N_NODES 200000
#define N_EDGES 6400000
#define HID 200
#define NREP 4                    // scatter accumulator replicas
#define GRID 256                  // persistent blocks (no cross-block deps)
#define MT 128                    // rows per tile
#define NTILES 1563               // ceil(200000/128)
#define ASTR 216                  // act stride (fp16): 432 B/row; 2-way bank alias (free)
#define AELEM (MT * ASTR)         // 27648 elems
#define ABYTES (AELEM * 2)        // 55296
#define ACHUNK (ABYTES / 16)      // 3456 16-B chunks
#define WSTR 232
#define WROWS 224
#define WELEMS (WROWS * WSTR)     // g_wph per-layer elems
#define SROWS 208                 // 13 n-tiles staged
#define SELEMS (SROWS * WSTR)     // 48256 elems = 96512 B
#define SCHUNK (SELEMS / 8)       // 6032 16-B chunks

// LDS: act [0,55296) ; wlds [55296,151808) ; h0s [151808,152320)
#define LDS_WOFF 55296
#define LDS_H0 151808
#define LDS_TOTAL 152320

typedef float f32x4 __attribute__((ext_vector_type(4)));
typedef _Float16 f16x8 __attribute__((ext_vector_type(8)));
typedef unsigned short u16;
typedef unsigned int u32;

__device__ __align__(16) float g_agg[NREP * N_NODES];
__device__ __align__(16) float g_wf[6 * HID * HID];      // fp32 (VALU fallback)
__device__ __align__(16) _Float16 g_wph[6 * WELEMS];     // fp16 W^T padded [l][n][k]
__device__ __align__(16) _Float16 g_act[(size_t)NTILES * AELEM];  // 86.4 MB ping buffer (in-place per tile)
__device__ int g_isbf;

__device__ __forceinline__ float bf2f(u16 u) {
  union { u32 i; float f; } v; v.i = ((u32)u) << 16; return v.f;
}
__device__ __forceinline__ u16 f2bf(float f) {  // RNE
  u32 i = __float_as_uint(f);
  return (u16)((i + 0x7FFFu + ((i >> 16) & 1u)) >> 16);
}
__device__ __forceinline__ float ldf(const void* p, int i, int isbf) {
  return isbf ? bf2f(((const u16*)p)[i]) : ((const float*)p)[i];
}
__device__ __forceinline__ void load_lds16(const void* g, void* l) {
  __builtin_amdgcn_global_load_lds(
      (const __attribute__((address_space(1))) u32*)g,
      (__attribute__((address_space(3))) u32*)l, 16, 0, 0);
}

// ---- rank-2 MFMA layout self-test (fp16), reference folded at compile time ----
constexpr int tf1(int m) { return (m & 3) + 1; }
constexpr int tf2(int m) { return ((m >> 2) & 3) + 2; }
constexpr int tg1(int k) { return (k & 7) + 1; }
constexpr int tg2(int k) { return ((k >> 3) & 3) + 1; }
constexpr int tu1(int k) { return ((k * 3) & 7) + 1; }
constexpr int tu2(int k) { return ((k >> 2) & 3) + 2; }
constexpr int tw1(int n) { return ((n * 5) & 7) + 1; }
constexpr int tw2(int n) { return ((n >> 2) & 3) + 1; }
constexpr int calcS(int i, int j) {
  int s = 0;
  for (int k = 0; k < 32; ++k)
    s += (i ? tg2(k) : tg1(k)) * (j ? tu2(k) : tu1(k));
  return s;
}
__device__ __forceinline__ float refD(int m, int n) {
  constexpr int S11 = calcS(0, 0), S12 = calcS(0, 1), S21 = calcS(1, 0), S22 = calcS(1, 1);
  return (float)(tf1(m) * tw1(n) * S11 + tf1(m) * tw2(n) * S12 +
                 tf2(m) * tw1(n) * S21 + tf2(m) * tw2(n) * S22);
}
__device__ int mfma_selftest(int l15, int q) {
  f16x8 av, bv;
#pragma unroll
  for (int j = 0; j < 8; ++j) {
    int k = q * 8 + j;
    av[j] = (_Float16)(float)(tf1(l15) * tg1(k) + tf2(l15) * tg2(k));
    bv[j] = (_Float16)(float)(tu1(k) * tw1(l15) + tu2(k) * tw2(l15));
  }
  f32x4 d = __builtin_amdgcn_mfma_f32_16x16x32_f16(av, bv, (f32x4){0.f, 0.f, 0.f, 0.f}, 0, 0, 0);
  bool ok0 = true, ok1 = true;
#pragma unroll
  for (int r = 0; r < 4; ++r) {
    ok0 = ok0 && (d[r] == refD(q * 4 + r, l15));
    ok1 = ok1 && (d[r] == refD(l15, q * 4 + r));
  }
  return __all(ok0) ? 0 : (__all(ok1) ? 1 : 2);
}

// ---- K0: dtype sniff ----
__global__ void sniff_kernel(const u32* __restrict__ xw) {
  int i = threadIdx.x;  // 64 threads
  u32 e = (xw[i] >> 7) & 0xFFu;
  unsigned long long b = __ballot(e >= 110u && e <= 135u);
  if (i == 0) g_isbf = (__popcll(b) >= 48) ? 1 : 0;
}

// ---- K1: zero replicas + both weight forms ----
__global__ void prep_kernel(const void* __restrict__ w_hid) {
  int t = blockIdx.x * blockDim.x + threadIdx.x;
  int isbf = g_isbf;
  if (t < NREP * N_NODES) g_agg[t] = 0.f;
  if (t < 6 * HID * HID) g_wf[t] = ldf(w_hid, t, isbf);
  if (t < 6 * WELEMS) {
    int l = t / WELEMS;
    int r = t - l * WELEMS;
    int n = r / WSTR;
    int k = r - n * WSTR;
    float v = 0.f;
    if (n < HID && k < HID) v = ldf(w_hid, (l * HID + k) * HID + n, isbf);
    g_wph[t] = (_Float16)v;
  }
}

// ---- K2: edge scatter-add (frozen) ----
__global__ void scatter_kernel(const int* __restrict__ ei, const void* __restrict__ x) {
  int t = blockIdx.x * blockDim.x + threadIdx.x;
  int e = t * 4;
  int isbf = g_isbf;
  float* agg = g_agg + (size_t)(blockIdx.x & (NREP - 1)) * N_NODES;
  bool is64 = ((ei[1] | ei[3] | ei[5] | ei[7]) == 0);
  int s0, s1, s2, s3, d0, d1, d2, d3;
  if (is64) {
    int4 a = *(const int4*)(ei + 2 * e);
    int4 b = *(const int4*)(ei + 2 * e + 4);
    int4 c = *(const int4*)(ei + 2 * N_EDGES + 2 * e);
    int4 d = *(const int4*)(ei + 2 * N_EDGES + 2 * e + 4);
    s0 = a.x; s1 = a.z; s2 = b.x; s3 = b.z;
    d0 = c.x; d1 = c.z; d2 = d.x; d3 = d.z;
  } else {
    int4 s4 = *(const int4*)(ei + e);
    int4 d4 = *(const int4*)(ei + N_EDGES + e);
    s0 = s4.x; s1 = s4.y; s2 = s4.z; s3 = s4.w;
    d0 = d4.x; d1 = d4.y; d2 = d4.z; d3 = d4.w;
  }
  atomicAdd(&agg[d0], ldf(x, s0, isbf));
  atomicAdd(&agg[d1], ldf(x, s1, isbf));
  atomicAdd(&agg[d2], ldf(x, s2, isbf));
  atomicAdd(&agg[d3], ldf(x, s3, isbf));
}

// ---- K3: persistent layer-major fused MLP ----
// 256 blocks x 1024 thr; block owns tiles t = bid, bid+256, ... (row-independent
// across layers -> no cross-block sync). Weights staged ONCE per block-layer.
__global__ __launch_bounds__(1024) void mlp_kernel(
    const void* __restrict__ x,
    const void* __restrict__ w_rel, const void* __restrict__ b_rel, const void* __restrict__ w_root,
    const void* __restrict__ w_in, const void* __restrict__ b_in,
    const void* __restrict__ b_hid, const void* __restrict__ w_out, const void* __restrict__ b_out,
    void* __restrict__ out) {
  extern __shared__ char smem[];
  _Float16* act = (_Float16*)smem;
  _Float16* wlds = (_Float16*)(smem + LDS_WOFF);
  float* h0s = (float*)(smem + LDS_H0);

  const int tid = threadIdx.x;
  const int isbf = g_isbf;
  const int lane = tid & 63;
  const int wv = tid >> 6;
  const int l15 = lane & 15;
  const int q = lane >> 4;
  const int band = wv >> 2;                 // 4 bands x 32 rows (Mt=2)
  const int g = wv & 3;                     // col groups: 4/3/3/3 n-tiles (13 total)
  const int ct0 = (g == 0) ? 0 : 4 + (g - 1) * 3;
  const int cnt = (g == 0) ? 4 : 3;

  const int mode = mfma_selftest(l15, q);

  if (mode < 2) {
    for (int l = 0; l < 6; ++l) {
      __syncthreads();  // prior layer's wlds/act LDS reads complete
      {                 // stage this layer's W^T once
        const _Float16* wg = g_wph + l * WELEMS;
        for (int c = tid; c < SCHUNK; c += 1024) load_lds16(wg + c * 8, wlds + c * 8);
      }
      bool pref = false;
      for (int t = blockIdx.x; t < NTILES; t += GRID) {
        const int nb = t * MT;
        if (l == 0) {
          // h0 (GraphConv) then act0 = relu(h0*w_in+b_in) straight into LDS
          if (tid < MT) {
            int node = nb + tid;
            float v = 0.f;
            if (node < N_NODES) {
              float a = g_agg[node] + g_agg[N_NODES + node] +
                        g_agg[2 * N_NODES + node] + g_agg[3 * N_NODES + node];
              v = a * ldf(w_rel, 0, isbf) + ldf(b_rel, 0, isbf) +
                  ldf(x, node, isbf) * ldf(w_root, 0, isbf);
            }
            h0s[tid] = v;
          }
          __syncthreads();  // h0 ready (+drains W stage on first tile)
          for (int idx = tid; idx < AELEM; idx += 1024) {
            int m = idx / ASTR, j = idx - m * ASTR;
            float v = 0.f;
            if (j < HID) {
              v = h0s[m] * ldf(w_in, j, isbf) + ldf(b_in, j, isbf);
              v = fmaxf(v, 0.f);
            }
            act[idx] = (_Float16)v;
          }
          __syncthreads();  // act ready
        } else {
          if (!pref) {      // first tile of layer: stage act here
            const _Float16* ga = g_act + (size_t)t * AELEM;
            for (int c = tid; c < ACHUNK; c += 1024) load_lds16(ga + c * 8, act + c * 8);
          }
          pref = false;
          __syncthreads();  // drains act stage (+W on first tile)
        }

        // ---- MFMA (core identical to R7) ----
        f32x4 acc[2][4];
#pragma unroll
        for (int h = 0; h < 2; ++h)
#pragma unroll
          for (int n = 0; n < 4; ++n) acc[h][n] = (f32x4){0.f, 0.f, 0.f, 0.f};

        const _Float16* ap = act + (band * 32 + l15) * ASTR + q * 8;
        const _Float16* bp = wlds + (ct0 * 16 + l15) * WSTR + q * 8;
#pragma unroll
        for (int ks = 0; ks < 7; ++ks) {
          f16x8 a0 = *(const f16x8*)(ap + ks * 32);
          f16x8 a1 = *(const f16x8*)(ap + 16 * ASTR + ks * 32);
#pragma unroll
          for (int n = 0; n < 4; ++n) {
            if (n < cnt) {
              f16x8 b = *(const f16x8*)(bp + n * 16 * WSTR + ks * 32);
              acc[0][n] = __builtin_amdgcn_mfma_f32_16x16x32_f16(a0, b, acc[0][n], 0, 0, 0);
              acc[1][n] = __builtin_amdgcn_mfma_f32_16x16x32_f16(a1, b, acc[1][n], 0, 0, 0);
            }
          }
        }
        __syncthreads();  // all LDS reads of this tile complete

        if (l < 5) {
          int tn = t + GRID;
          if (tn < NTILES) {  // prefetch next tile's act; latency hides under epilogue
            const _Float16* ga = g_act + (size_t)tn * AELEM;
            for (int c = tid; c < ACHUNK; c += 1024) load_lds16(ga + c * 8, act + c * 8);
            pref = true;
          }
          // epilogue: bias+relu -> global (in-place tile slot; LDS copy already consumed)
          _Float16* go = g_act + (size_t)t * AELEM;
#pragma unroll
          for (int n = 0; n < 4; ++n) {
            if (n < cnt) {
              int ctile = (ct0 + n) * 16;
#pragma unroll
              for (int h = 0; h < 2; ++h) {
#pragma unroll
                for (int r = 0; r < 4; ++r) {
                  int rr = (mode == 0) ? (q * 4 + r) : l15;
                  int cc = (mode == 0) ? l15 : (q * 4 + r);
                  int row = band * 32 + h * 16 + rr, col = ctile + cc;
                  float v = acc[h][n][r] + ((col < HID) ? ldf(b_hid, l * HID + col, isbf) : 0.f);
                  go[row * ASTR + col] = (_Float16)fmaxf(v, 0.f);
                }
              }
            }
          }
        } else {
          // final hidden layer: epilogue -> LDS, then fused output layer
#pragma unroll
          for (int n = 0; n < 4; ++n) {
            if (n < cnt) {
              int ctile = (ct0 + n) * 16;
#pragma unroll
              for (int h = 0; h < 2; ++h) {
#pragma unroll
                for (int r = 0; r < 4; ++r) {
                  int rr = (mode == 0) ? (q * 4 + r) : l15;
                  int cc = (mode == 0) ? l15 : (q * 4 + r);
                  int row = band * 32 + h * 16 + rr, col = ctile + cc;
                  float v = acc[h][n][r] + ((col < HID) ? ldf(b_hid, l * HID + col, isbf) : 0.f);
                  act[row * ASTR + col] = (_Float16)fmaxf(v, 0.f);
                }
              }
            }
          }
          __syncthreads();
          // output: 8 threads/row x 25 cols
          {
            int m = tid >> 3, c = tid & 7;
            const _Float16* ar = act + m * ASTR;
            float s = 0.f;
#pragma unroll
            for (int j = c * 25; j < c * 25 + 25; ++j)
              s += (float)ar[j] * ldf(w_out, j, isbf);
            s += __shfl_down(s, 4);
            s += __shfl_down(s, 2);
            s += __shfl_down(s, 1);
            int node = nb + m;
            if (c == 0 && node < N_NODES) {
              float logit = s + ldf(b_out, 0, isbf);
              float o = 1.f / (1.f + __expf(-logit));
              if (isbf) ((u16*)out)[node] = f2bf(o);
              else ((float*)out)[node] = o;
            }
          }
          __syncthreads();  // output reads done before next tile's staging
        }
      }
    }
  } else {
    // ---- VALU fallback (defensive): per-tile R4-style, 2 passes of 64 rows ----
    float(*fA)[201] = (float(*)[201])smem;
    float(*fB)[201] = (float(*)[201])(smem + 64 * 201 * 4);
    for (int t = blockIdx.x; t < NTILES; t += GRID) {
      for (int p = 0; p < 2; ++p) {
        int nb = t * MT + p * 64;
        __syncthreads();
        if (tid < 64) {
          int node = nb + tid;
          float v = 0.f;
          if (node < N_NODES) {
            float a = g_agg[node] + g_agg[N_NODES + node] +
                      g_agg[2 * N_NODES + node] + g_agg[3 * N_NODES + node];
            v = a * ldf(w_rel, 0, isbf) + ldf(b_rel, 0, isbf) +
                ldf(x, node, isbf) * ldf(w_root, 0, isbf);
          }
          h0s[tid] = v;
        }
        __syncthreads();
        for (int i = tid; i < 64 * HID; i += 1024) {
          int mm = i / HID, ff = i - mm * HID;
          float v = h0s[mm] * ldf(w_in, ff, isbf) + ldf(b_in, ff, isbf);
          fA[mm][ff] = v > 0.f ? v : 0.f;
        }
        __syncthreads();
        const int m = tid >> 4, c = tid & 15;
        float(*ain)[201] = fA;
        float(*aout)[201] = fB;
        for (int l = 0; l < 6; ++l) {
          float acc[13];
#pragma unroll
          for (int jj = 0; jj < 13; ++jj) {
            int j = c * 13 + jj;
            acc[jj] = (j < HID) ? ldf(b_hid, l * HID + j, isbf) : 0.f;
          }
          const float* wl = g_wf + l * HID * HID;
          for (int k = 0; k < HID; ++k) {
            float a = ain[m][k];
            const float* wr = wl + k * HID;
#pragma unroll
            for (int jj = 0; jj < 13; ++jj) {
              int j = c * 13 + jj;
              if (j < HID) acc[jj] = fmaf(a, wr[j], acc[jj]);
            }
          }
          __syncthreads();
#pragma unroll
          for (int jj = 0; jj < 13; ++jj) {
            int j = c * 13 + jj;
            if (j < HID) aout[m][j] = fmaxf(acc[jj], 0.f);
          }
          float(*tsw)[201] = ain; ain = aout; aout = tsw;
          __syncthreads();
        }
        float s = 0.f;
        for (int j = c * 13; j < c * 13 + 13 && j < HID; ++j)
          s += ain[m][j] * ldf(w_out, j, isbf);
        s += __shfl_down(s, 8);
        s += __shfl_down(s, 4);
        s += __shfl_down(s, 2);
        s += __shfl_down(s, 1);
        int node = nb + m;
        if (c == 0 && node < N_NODES) {
          float logit = s + ldf(b_out, 0, isbf);
          float o = 1.f / (1.f + __expf(-logit));
          if (isbf) ((u16*)out)[node] = f2bf(o);
          else ((float*)out)[node] = o;
        }
      }
    }
  }
}

extern "C" void kernel_launch(void* const* d_in, const int* in_sizes, int n_in,
                              void* d_out, int out_size, void* d_ws, size_t ws_size,
                              hipStream_t stream) {
  const void* x      = d_in[0];
  const int* ei      = (const int*)d_in[1];
  const void* w_rel  = d_in[2];
  const void* b_rel  = d_in[3];
  const void* w_root = d_in[4];
  const void* w_in   = d_in[5];
  const void* b_in   = d_in[6];
  const void* w_hid  = d_in[7];
  const void* b_hid  = d_in[8];
  const void* w_out  = d_in[9];
  const void* b_out  = d_in[10];
  (void)d_ws; (void)ws_size; (void)in_sizes; (void)n_in; (void)out_size;

  sniff_kernel<<<1, 64, 0, stream>>>((const u32*)x);
  prep_kernel<<<(NREP * N_NODES + 255) / 256, 256, 0, stream>>>(w_hid);
  scatter_kernel<<<N_EDGES / 4 / 256, 256, 0, stream>>>(ei, x);
  mlp_kernel<<<GRID, 1024, LDS_TOTAL, stream>>>(
      x, w_rel, b_rel, w_root, w_in, b_in, b_hid, w_out, b_out, d_out);
}